// Round 6
// baseline (270.695 us; speedup 1.0000x reference)
//
#include <hip/hip_runtime.h>

// CustomRNN: B=2048, T=512, I=1, H=64.
// Round-6 structure: BARRIER-FREE register-resident recurrence.
//   One wave (64 threads) owns 16 batches and ALL 64 h-rows as 4 MFMA
//   M-tiles with a permuted row map:
//     tile m, within-tile row c -> global row r = 8*(c>>2)+(c&3)+4*(m&1)+32*(m>>1)
//   D layout (verified r3/r5: col=lane&15, row=q*4+reg) then gives lane (q,col)
//   rows {8q..8q+7} (tiles 0,1) and {32+8q..32+8q+7} (tiles 2,3) for batch col —
//   exactly its own next-step B-fragment B[k=q*8+j][n=col] (verified layout).
//   => h never leaves registers: mfma -> tanh -> pkrtz -> mfma. No LDS H, no
//   __syncthreads anywhere (round-5 PMC: ~560 of 741 cyc/step was barrier
//   stall; this removes it structurally).
// Numerics: W_hh as fp16 hi + 4096*lo (lo unscaled would be fp16-subnormal ->
//   flush risk); h in plain fp16 (est. ~1e-3 final err vs 7.9e-3 threshold).
//   Accumulate + tanh in fp32 (exp2 + pairwise-shared rcp).
// x staged once to LDS as [t4][batch] float4; one ds_read_b128 per 4 steps,
//   prefetched one t4 ahead (off critical path).

typedef _Float16 v8h  __attribute__((ext_vector_type(8)));
typedef __fp16   v2hp __attribute__((ext_vector_type(2)));   // pkrtz result
typedef float    v2f  __attribute__((ext_vector_type(2)));
typedef float    v4f  __attribute__((ext_vector_type(4)));
typedef int      v4i  __attribute__((ext_vector_type(4)));

#define TMAX 512

__global__ __launch_bounds__(64)
__attribute__((amdgpu_waves_per_eu(1, 1)))
void rnn_reg(
    const float* __restrict__ x,      // [B, T]
    const float* __restrict__ W_ih,   // [64, 1]
    const float* __restrict__ W_hh,   // [64, 64]
    const float* __restrict__ b_ih,   // [64]
    const float* __restrict__ b_hh,   // [64]
    const float* __restrict__ fc_w,   // [1, 64]
    const float* __restrict__ fc_b,   // [1]
    float* __restrict__ out,          // [B, 1]
    int B, int T)
{
    const int lane = threadIdx.x;     // 0..63, one wave per block
    const int q    = lane >> 4;
    const int col  = lane & 15;
    const int batch0 = blockIdx.x * 16;

    __shared__ __align__(16) float4 xs[TMAX / 4 + 1][16];  // [t4][batch]

    // ---- one-time x staging (transposed, float4 along t) ----
    const int TqF  = T >> 2;
    const int tail = T & 3;
    const int TqA  = TqF + (tail ? 1 : 0);
    for (int u = lane; u < 16 * TqA; u += 64) {
        const int b  = u & 15;
        const int t4 = u >> 4;
        const int gb = batch0 + b;
        float4 v = make_float4(0.f, 0.f, 0.f, 0.f);
        if (gb < B) {
            const float* xp = x + (size_t)gb * T + 4 * t4;
            if (((T & 3) == 0) || (4 * t4 + 3 < T)) {
                v = *(const float4*)xp;
            } else {
                if (4 * t4 + 0 < T) v.x = xp[0];
                if (4 * t4 + 1 < T) v.y = xp[1];
                if (4 * t4 + 2 < T) v.z = xp[2];
            }
        }
        xs[t4][b] = v;
    }

    // ---- A fragments: lane (q,col) holds A[c=col][k=8q+j] of tile m ----
    v8h Ah[4][2], Al[4][2];
#pragma unroll
    for (int m = 0; m < 4; ++m) {
        const int r = 8 * (col >> 2) + (col & 3) + 4 * (m & 1) + 32 * (m >> 1);
        const float* wrow = W_hh + (size_t)r * 64;
#pragma unroll
        for (int kt = 0; kt < 2; ++kt) {
            const float4 w0 = *(const float4*)(wrow + kt * 32 + 8 * q);
            const float4 w1 = *(const float4*)(wrow + kt * 32 + 8 * q + 4);
            const float wf[8] = {w0.x, w0.y, w0.z, w0.w, w1.x, w1.y, w1.z, w1.w};
#pragma unroll
            for (int j = 0; j < 8; ++j) {
                const _Float16 hi = (_Float16)wf[j];
                Ah[m][kt][j] = hi;
                Al[m][kt][j] = (_Float16)((wf[j] - (float)hi) * 4096.0f);
            }
        }
    }
    // per-lane D-row constants: rows r(m, 4q+i) = 8q + i + 4*(m&1) + 32*(m>>1)
    float bias[4][4], wih[4][4], fcw[4][4];
#pragma unroll
    for (int m = 0; m < 4; ++m)
#pragma unroll
        for (int i = 0; i < 4; ++i) {
            const int r = 8 * q + i + 4 * (m & 1) + 32 * (m >> 1);
            bias[m][i] = b_ih[r] + b_hh[r];
            wih[m][i]  = W_ih[r];
            fcw[m][i]  = fc_w[r];
        }

    // ---- register-resident recurrence ----
    v8h bh0 = {}, bh1 = {};   // h fragments (k 0..31 / 32..63), start at 0
    float th[4][4];           // last step's tanh outputs (fp32, for fc)

    auto step = [&](float xv) {
        v4f acc[4], accl[4];
#pragma unroll
        for (int m = 0; m < 4; ++m) {
            v4f c;
#pragma unroll
            for (int i = 0; i < 4; ++i)
                c[i] = __builtin_fmaf(xv, wih[m][i], bias[m][i]);
            acc[m]  = __builtin_amdgcn_mfma_f32_16x16x32_f16(Ah[m][0], bh0, c, 0, 0, 0);
            acc[m]  = __builtin_amdgcn_mfma_f32_16x16x32_f16(Ah[m][1], bh1, acc[m], 0, 0, 0);
            const v4f z = {0.f, 0.f, 0.f, 0.f};
            accl[m] = __builtin_amdgcn_mfma_f32_16x16x32_f16(Al[m][0], bh0, z, 0, 0, 0);
            accl[m] = __builtin_amdgcn_mfma_f32_16x16x32_f16(Al[m][1], bh1, accl[m], 0, 0, 0);
        }
        int pk[8];
#pragma unroll
        for (int m = 0; m < 4; ++m) {
#pragma unroll
            for (int h2 = 0; h2 < 2; ++h2) {
                const int i0 = 2 * h2;
                const v2f a2 = { __builtin_fmaf(accl[m][i0],     2.44140625e-4f, acc[m][i0]),
                                 __builtin_fmaf(accl[m][i0 + 1], 2.44140625e-4f, acc[m][i0 + 1]) };
                // tanh(a) = 1 - 2/(1 + exp(2a)); rcp shared across the pair
                const v2f ein = a2 * 2.885390081777927f;           // 2a/ln2
                const v2f e   = { __builtin_amdgcn_exp2f(ein.x),
                                  __builtin_amdgcn_exp2f(ein.y) };
                const v2f u   = e + 1.0f;
                const float nr = -2.0f * __builtin_amdgcn_rcpf(u.x * u.y);
                const v2f us  = __builtin_shufflevector(u, u, 1, 0);
                const v2f nrv = { nr, nr };
                const v2f one = { 1.0f, 1.0f };
                const v2f t2  = __builtin_elementwise_fma(us, nrv, one);
                th[m][i0]     = t2.x;
                th[m][i0 + 1] = t2.y;
                pk[m * 2 + h2] = __builtin_bit_cast(int,
                                     __builtin_amdgcn_cvt_pkrtz(t2.x, t2.y));
            }
        }
        const v4i lo = { pk[0], pk[1], pk[2], pk[3] };   // tiles 0,1 -> k 0..31
        const v4i hi = { pk[4], pk[5], pk[6], pk[7] };   // tiles 2,3 -> k 32..63
        bh0 = __builtin_bit_cast(v8h, lo);
        bh1 = __builtin_bit_cast(v8h, hi);
    };

    float4 xq = xs[0][col];
    for (int t4 = 0; t4 < TqF; ++t4) {
        const int nt = (t4 + 1 < TqA) ? t4 + 1 : 0;
        const float4 xn = xs[nt][col];   // prefetch next quad (off critical path)
        step(xq.x); step(xq.y); step(xq.z); step(xq.w);
        xq = xn;
    }
    if (tail > 0) step(xq.x);
    if (tail > 1) step(xq.y);
    if (tail > 2) step(xq.z);

    // ---- fc epilogue: out[b] = sum_r fc_w[r] * h[r][b] + fc_b ----
    float v = 0.f;
#pragma unroll
    for (int m = 0; m < 4; ++m)
#pragma unroll
        for (int i = 0; i < 4; ++i)
            v = __builtin_fmaf(th[m][i], fcw[m][i], v);
    v += __shfl_xor(v, 16, 64);   // combine the 4 q-lanes of this col
    v += __shfl_xor(v, 32, 64);
    if (lane < 16 && batch0 + lane < B) out[batch0 + lane] = v + fc_b[0];
}

extern "C" void kernel_launch(void* const* d_in, const int* in_sizes, int n_in,
                              void* d_out, int out_size, void* d_ws, size_t ws_size,
                              hipStream_t stream) {
    const float* x    = (const float*)d_in[0];
    const float* W_ih = (const float*)d_in[1];
    const float* W_hh = (const float*)d_in[2];
    const float* b_ih = (const float*)d_in[3];
    const float* b_hh = (const float*)d_in[4];
    const float* fc_w = (const float*)d_in[5];
    const float* fc_b = (const float*)d_in[6];
    float* out = (float*)d_out;

    const int B = out_size;          // output is [B, 1]
    const int T = in_sizes[0] / B;   // I == 1

    const int blocks = (B + 15) / 16;
    rnn_reg<<<blocks, 64, 0, stream>>>(x, W_ih, W_hh, b_ih, b_hh,
                                       fc_w, fc_b, out, B, T);
}